// Round 7
// baseline (167.814 us; speedup 1.0000x reference)
//
#include <hip/hip_runtime.h>
#include <hip/hip_bf16.h>
#include <stdint.h>

#define B_   4
#define N_   10000
#define K_   16
#define D_   256
#define OUT_ 256
#define M_   (B_ * N_)          // 40000
#define CW   32                 // bf16 cols per y2 chunk (64-B rows)
#define NCH  8                  // chunks (one per XCD)
#define CHUNK_ELEMS ((size_t)M_ * CW)   // 1,280,000 ushorts = 2.56 MB
#define T64_ 625                // M / 64 m-tiles, exact

typedef __attribute__((ext_vector_type(8))) short          short8;    // MFMA frag
typedef __attribute__((ext_vector_type(8))) unsigned short ushort8;
typedef __attribute__((ext_vector_type(4))) float          f32x4;
typedef __attribute__((ext_vector_type(4))) unsigned short ushort4_t;

__device__ inline unsigned short f2bf(float f) {
    __hip_bfloat16 h = __float2bfloat16(f);
    return *reinterpret_cast<unsigned short*>(&h);
}
__device__ inline float bf2f(unsigned short u) {
    unsigned int v = ((unsigned int)u) << 16;
    return __builtin_bit_cast(float, v);
}

// ---------------------------------------------------------------------------
// wprep (R5 version, correctness-proven): W (256 x 512 f32, o = [W1_o|W2_o])
// -> WbF bf16 FRAG-MAJOR: WbF[((o16*8 + kf)*64 + lane)*8 + e] =
//   W'[o16*16 + (lane&15)][kf*32 + (lane>>4)*8 + e]
// Each (o16,kf) fragment = one coalesced 16-B load per lane, directly in
// mfma_16x16x32 operand layout. W'[o'] = o'<256 ? W[o'][0:256]
// : W[o'-256][256:512].  Total 256 KB (L2/L3-hot for the GEMM).
// ---------------------------------------------------------------------------
__global__ __launch_bounds__(256) void wprep(const float* __restrict__ W,
                                             unsigned short* __restrict__ WbF) {
    const int u  = blockIdx.x * 256 + threadIdx.x;   // 0..32767, 4 elems each
    const int e0 = (u & 1) * 4;
    const int l  = (u >> 1) & 63;
    const int v  = u >> 7;
    const int kf = v & 7;
    const int o16 = v >> 3;                          // 0..31
    const int op  = o16 * 16 + (l & 15);             // 0..511
    const int k   = kf * 32 + (l >> 4) * 8 + e0;     // 0..255
    const int row = (op < OUT_) ? op : op - OUT_;
    const int col = (op < OUT_) ? k : 256 + k;
    const float4 w4 = *(const float4*)(W + (size_t)row * 512 + col);
    ushort4_t s;
    s.x = f2bf(w4.x); s.y = f2bf(w4.y); s.z = f2bf(w4.z); s.w = f2bf(w4.w);
    *(ushort4_t*)(WbF + (size_t)u * 4) = s;
}

// ---------------------------------------------------------------------------
// gemm_nl: y[m, o'] = x[m, :] . W'[o', :]   (M=40000, K=256, N'=512)
// ZERO LDS, ZERO barriers (every LDS-staged variant was pinned at 43-56 us
// by the per-k-step vmcnt(0) barrier drain). Wave = 16 m-rows x 64 o-cols;
// per k-step: 2 per-lane x float4 loads (R5-proven pattern) + 4 TRANSIENT
// B-fragment loads from frag-major WbF (L2-hot; transient => no R5 regalloc
// failure) + cvt + 4 swapped MFMA. Fully unrolled 8 steps -> 48 independent
// loads for the scheduler; latency hidden by ILP + ~20 blocks/CU supply.
// Col-split: 8 col-blocks (64 cols) per m-tile, all pinned to ONE XCD
// (bi % 8 == m-tile % 8) so x is HBM-fetched once, siblings hit L2.
// Swapped mfma(b,a): D[row=o, col=m] ->
//   cb<4 : y1 fp32 m-row-major via coalesced 16-B f32x4 stores
//   cb>=4: y2 bf16 CW32 chunk-major packed ushort4 stores (R3/R6-proven)
// ---------------------------------------------------------------------------
__global__ __launch_bounds__(256) void gemm_nl(const float* __restrict__ x,
                                               const unsigned short* __restrict__ WbF,
                                               float* __restrict__ y1,
                                               unsigned short* __restrict__ y2c) {
    const int tid  = threadIdx.x;
    const int wid  = tid >> 6;
    const int lane = tid & 63;
    const int q    = lane >> 4;
    const int r16  = lane & 15;

    // bi = t*8 + r ; m-tile g = (t>>3)*8 + r  (all 8 col-blocks of g share an
    // XCD under the bi%8 round-robin heuristic); cb = t&7.
    const int bi = blockIdx.x;
    const int r  = bi & 7;
    const int t  = bi >> 3;
    const int g  = (t >> 3) * 8 + r;
    const int cb = t & 7;
    if (g >= T64_) return;
    const int m0 = g * 64 + wid * 16;          // wave's 16 m-rows

    const float* xr = x + (size_t)(m0 + r16) * D_ + q * 8;

    f32x4 acc[4] = {};

#pragma unroll
    for (int kf = 0; kf < 8; ++kf) {
        // per-lane A loads (row=r16, k = kf*32 + q*8 + e) — R5-proven layout
        const float4 x0 = *(const float4*)(xr + kf * 32);
        const float4 x1 = *(const float4*)(xr + kf * 32 + 4);
        // transient B fragments (o16 = cb*4 + j), coalesced 1-KB loads, L2-hot
        short8 bfr[4];
#pragma unroll
        for (int j = 0; j < 4; ++j)
            bfr[j] = *(const short8*)(
                WbF + (size_t)((cb * 4 + j) * 8 + kf) * 512 + lane * 8);

        short8 a;
        a[0] = (short)f2bf(x0.x); a[1] = (short)f2bf(x0.y);
        a[2] = (short)f2bf(x0.z); a[3] = (short)f2bf(x0.w);
        a[4] = (short)f2bf(x1.x); a[5] = (short)f2bf(x1.y);
        a[6] = (short)f2bf(x1.z); a[7] = (short)f2bf(x1.w);

#pragma unroll
        for (int j = 0; j < 4; ++j)
            acc[j] = __builtin_amdgcn_mfma_f32_16x16x32_bf16(bfr[j], a, acc[j], 0, 0, 0);
    }

    // ---- epilogue: D[row = q*4+reg (o), col = r16 (m)] ----
    if (cb < 4) {
        // y1 fp32 m-row-major: per j one 16-B f32x4 store per lane,
        // (q,r16) lanes tile 16 rows x 64 B -> fully coalesced.
        float* yrow = y1 + (size_t)(m0 + r16) * OUT_ + cb * 64 + q * 4;
#pragma unroll
        for (int j = 0; j < 4; ++j)
            *(f32x4*)(yrow + j * 16) = acc[j];
    } else {
        // y2 bf16 CW32 chunk-major packed stores (proven R3/R6 epilogue)
        const int m  = m0 + r16;
        const int bb = (m >= N_) + (m >= 2 * N_) + (m >= 3 * N_);
        const int n  = m - bb * N_;
        unsigned short* rb = y2c + (size_t)(n * B_ + bb) * CW;
#pragma unroll
        for (int j = 0; j < 4; ++j) {
            const int o2  = (cb - 4) * 64 + j * 16 + q * 4;  // 4 consecutive cols
            const int cch = o2 >> 5;
            const int col = o2 & 31;
            ushort4_t p;
            p.x = f2bf(acc[j][0]); p.y = f2bf(acc[j][1]);
            p.z = f2bf(acc[j][2]); p.w = f2bf(acc[j][3]);
            *(ushort4_t*)(rb + (size_t)cch * CHUNK_ELEMS + col) = p;
        }
    }
}

// ---------------------------------------------------------------------------
// gather_out (unchanged from R6): out[b,n,o] =
//   relu( y1[b,n,o] + (1/cnt) sum_k y2[b,neigh[n,k],o] + bias[o] )
// Chunk c = blockIdx&7 -> XCD; 2.56-MB y2 chunk L2-resident; NT y1 loads
// (read-once stream must not evict the gather chunk); NT out stores.
// ---------------------------------------------------------------------------
__global__ __launch_bounds__(256) void gather_out(const unsigned short* __restrict__ y2c,
                                                  const float* __restrict__ y1,
                                                  const int*   __restrict__ neigh,
                                                  const float* __restrict__ bias,
                                                  float* __restrict__ out) {
    const int c   = blockIdx.x & 7;
    const int g   = blockIdx.x >> 3;
    const int n0  = g * 16;
    const int tid = threadIdx.x;

    __shared__ int   idx_s[16 * K_];   // 256 ints
    __shared__ float inv_s[16];

    idx_s[tid] = neigh[n0 * K_ + tid];
    __syncthreads();
    if (tid < 16) {
        int cnt = 0;
#pragma unroll
        for (int k = 0; k < K_; ++k) cnt += idx_s[tid * K_ + k] >= 0 ? 1 : 0;
        inv_s[tid] = 1.0f / (float)(cnt > 1 ? cnt : 1);
    }
    __syncthreads();

    const int q  = tid & 3;          // 8-col group within the 32-col chunk
    const int tl = tid >> 2;         // task 0..63
    const int ns = tl >> 2;          // node_sub 0..15
    const int b  = tl & 3;           // batch

    const unsigned short* ycc = y2c + (size_t)c * CHUNK_ELEMS;

    int jj[K_];
#pragma unroll
    for (int k = 0; k < K_; ++k) jj[k] = idx_s[ns * K_ + k];

    // 16 independent 16-B gather loads from the L2-resident chunk
    ushort8 vv[K_];
#pragma unroll
    for (int k = 0; k < K_; ++k) {
        const int jc = jj[k] >= 0 ? jj[k] : 0;
        vv[k] = *(const ushort8*)(ycc + ((size_t)jc * B_ + b) * CW + q * 8);
    }

    // streaming self term (NT: read-once, keep L2 for the chunk) + bias
    const size_t mo = (size_t)(b * N_ + n0 + ns) * OUT_ + c * CW + q * 8;
    const f32x4 s0 = __builtin_nontemporal_load((const f32x4*)(y1 + mo));
    const f32x4 s1 = __builtin_nontemporal_load((const f32x4*)(y1 + mo + 4));
    const f32x4 b0 = *(const f32x4*)(bias + c * CW + q * 8);
    const f32x4 b1 = *(const f32x4*)(bias + c * CW + q * 8 + 4);

    float acc[8] = {0.f, 0.f, 0.f, 0.f, 0.f, 0.f, 0.f, 0.f};
#pragma unroll
    for (int k = 0; k < K_; ++k) {
        const float m = jj[k] >= 0 ? 1.f : 0.f;
#pragma unroll
        for (int e = 0; e < 8; ++e) acc[e] += bf2f(vv[k][e]) * m;
    }
    const float inv = inv_s[ns];

    f32x4 o0, o1;
#pragma unroll
    for (int e = 0; e < 4; ++e) {
        float v0 = acc[e] * inv + s0[e] + b0[e];
        float v1 = acc[e + 4] * inv + s1[e] + b1[e];
        o0[e] = v0 > 0.f ? v0 : 0.f;
        o1[e] = v1 > 0.f ? v1 : 0.f;
    }
    // out is never re-read: nontemporal stores
    __builtin_nontemporal_store(o0, (f32x4*)(out + mo));
    __builtin_nontemporal_store(o1, (f32x4*)(out + mo + 4));
}

// ---------------------------------------------------------------------------
extern "C" void kernel_launch(void* const* d_in, const int* in_sizes, int n_in,
                              void* d_out, int out_size, void* d_ws, size_t ws_size,
                              hipStream_t stream) {
    const float* x     = (const float*)d_in[0];   // (4, 10000, 256) fp32
    const int*   neigh = (const int*)d_in[1];     // (10000, 16) int32
    const float* W     = (const float*)d_in[2];   // (256, 512) fp32
    const float* bias  = (const float*)d_in[3];   // (256,) fp32
    float*       out   = (float*)d_out;           // (4, 10000, 256) fp32

    unsigned short* WbF = (unsigned short*)d_ws;              // 256 KB frag-major
    float*          y1  = (float*)(WbF + 131072);             // 40000*256 f32 = 41 MB
    unsigned short* y2c = (unsigned short*)(y1 + (size_t)M_ * OUT_);  // 8 x 2.56 MB

    wprep<<<128, 256, 0, stream>>>(W, WbF);
    // grid = 632 t-slots x 8 : (t>>3)*8 + (bi&7) = m-tile, t&7 = col-block
    gemm_nl<<<632 * 8, 256, 0, stream>>>(x, WbF, y1, y2c);    // 5056 blocks
    gather_out<<<(N_ / 16) * NCH, 256, 0, stream>>>(y2c, y1, neigh, bias, out);
}

// Round 8
// 155.916 us; speedup vs baseline: 1.0763x; 1.0763x over previous
//
#include <hip/hip_runtime.h>
#include <hip/hip_bf16.h>
#include <stdint.h>

#define B_   4
#define N_   10000
#define K_   16
#define D_   256
#define OUT_ 256
#define M_   (B_ * N_)          // 40000
#define CW   32                 // bf16 cols per y2 chunk (64-B rows)
#define NCH  8                  // chunks (one per XCD)
#define CHUNK_ELEMS ((size_t)M_ * CW)   // 1,280,000 ushorts = 2.56 MB
#define T64_ 625                // M / 64 m-groups, exact

typedef __attribute__((ext_vector_type(8))) short          short8;    // MFMA frag
typedef __attribute__((ext_vector_type(8))) unsigned short ushort8;
typedef __attribute__((ext_vector_type(4))) float          f32x4;
typedef __attribute__((ext_vector_type(4))) unsigned short ushort4_t;

__device__ inline unsigned short f2bf(float f) {
    __hip_bfloat16 h = __float2bfloat16(f);
    return *reinterpret_cast<unsigned short*>(&h);
}
__device__ inline float bf2f(unsigned short u) {
    unsigned int v = ((unsigned int)u) << 16;
    return __builtin_bit_cast(float, v);
}

// ---------------------------------------------------------------------------
// wprep (R5/R7 version, correctness-proven): W (256x512 f32, o = [W1_o|W2_o])
// -> WbF bf16 FRAG-MAJOR: WbF[((o16*8 + kf)*64 + lane)*8 + e] =
//   W'[o16*16 + (lane&15)][kf*32 + (lane>>4)*8 + e]
// W'[o'] = o'<256 ? W[o'][0:256] : W[o'-256][256:512].  Total 256 KB.
// o16 outermost => the 4 o16s of col-block cb form ONE contiguous 32-KB slab
// (WbF + cb*16384), which gemm_pb copies linearly into LDS.
// ---------------------------------------------------------------------------
__global__ __launch_bounds__(256) void wprep(const float* __restrict__ W,
                                             unsigned short* __restrict__ WbF) {
    const int u  = blockIdx.x * 256 + threadIdx.x;   // 0..32767, 4 elems each
    const int e0 = (u & 1) * 4;
    const int l  = (u >> 1) & 63;
    const int v  = u >> 7;
    const int kf = v & 7;
    const int o16 = v >> 3;                          // 0..31
    const int op  = o16 * 16 + (l & 15);             // 0..511
    const int k   = kf * 32 + (l >> 4) * 8 + e0;     // 0..255
    const int row = (op < OUT_) ? op : op - OUT_;
    const int col = (op < OUT_) ? k : 256 + k;
    const float4 w4 = *(const float4*)(W + (size_t)row * 512 + col);
    ushort4_t s;
    s.x = f2bf(w4.x); s.y = f2bf(w4.y); s.z = f2bf(w4.z); s.w = f2bf(w4.w);
    *(ushort4_t*)(WbF + (size_t)u * 4) = s;
}

// ---------------------------------------------------------------------------
// gemm_pb: y[m, o'] = x[m, :] . W'[o', :]   (M=40000, K=256, N'=512)
// PERSISTENT COL-BLOCK, B-IN-LDS-ONCE, ZERO-BARRIER m-LOOP.
//  - Fixes the LDS-variants' per-k-step barrier drain (B staged ONCE; the
//    only __syncthreads is before the loop).
//  - Fixes R7's L2-BW bound (B re-read per wave per k-step = 647 MB): B is
//    read from L2 once per block (32 KB), then served from LDS.
// Block = 4 waves; wave = 16 m-rows x 64 o-cols per iteration.
// Grid 1024 = 8 col-blocks x 128 m-slots; bi = cb*128 + s => bi%8 = s%8, so
// all 8 col-blocks of m-slot s share an XCD: x HBM-fetched once, siblings L2.
// Slot s handles m-groups g = s, s+128, ... (< 625; 64 rows each, exact).
// Per wave-iter: 16 upfront independent x float4 loads (R5/R7-proven layout)
// -> cvt -> 32 contiguous conflict-free ds_read_b128 -> 32 swapped MFMA.
// Epilogue identical to R7 (harness-verified):
//   cb<4 : y1 fp32 m-row-major coalesced f32x4 stores
//   cb>=4: y2 bf16 CW32 chunk-major packed ushort4 stores
// ---------------------------------------------------------------------------
__global__ __launch_bounds__(256) void gemm_pb(const float* __restrict__ x,
                                               const unsigned short* __restrict__ WbF,
                                               float* __restrict__ y1,
                                               unsigned short* __restrict__ y2c) {
    __shared__ unsigned short Bs[16384];   // 32 KB: col-block's 64o x 256k

    const int tid  = threadIdx.x;
    const int wid  = tid >> 6;
    const int lane = tid & 63;
    const int q    = lane >> 4;
    const int r16  = lane & 15;

    const int bi = blockIdx.x;
    const int s  = bi & 127;       // m-slot (XCD = s%8 for all col-blocks)
    const int cb = bi >> 7;        // col-block 0..7

    // ---- stage B slab once: linear 32-KB copy of WbF[cb*16384 ..] ----
    {
        const unsigned short* wsrc = WbF + (size_t)cb * 16384 + tid * 8;
#pragma unroll
        for (int i2 = 0; i2 < 8; ++i2) {
            __builtin_amdgcn_global_load_lds(
                (const __attribute__((address_space(1))) void*)(wsrc + i2 * 2048),
                (__attribute__((address_space(3))) void*)(Bs + tid * 8 + i2 * 2048),
                16, 0, 0);
        }
    }
    __syncthreads();               // the ONLY barrier in the kernel

    for (int g = s; g < T64_; g += 128) {
        const int m0 = g * 64 + wid * 16;
        const float* xr = x + (size_t)(m0 + r16) * D_ + q * 8;

        // 16 independent x loads issued upfront (compiler inserts fine
        // vmcnt waits per use; load kf's latency hides under kf-1 compute)
        float4 xb[16];
#pragma unroll
        for (int kf = 0; kf < 8; ++kf) {
            xb[2 * kf]     = *(const float4*)(xr + kf * 32);
            xb[2 * kf + 1] = *(const float4*)(xr + kf * 32 + 4);
        }

        f32x4 acc[4] = {};
#pragma unroll
        for (int kf = 0; kf < 8; ++kf) {
            short8 a;
            a[0] = (short)f2bf(xb[2 * kf].x);     a[1] = (short)f2bf(xb[2 * kf].y);
            a[2] = (short)f2bf(xb[2 * kf].z);     a[3] = (short)f2bf(xb[2 * kf].w);
            a[4] = (short)f2bf(xb[2 * kf + 1].x); a[5] = (short)f2bf(xb[2 * kf + 1].y);
            a[6] = (short)f2bf(xb[2 * kf + 1].z); a[7] = (short)f2bf(xb[2 * kf + 1].w);
#pragma unroll
            for (int j = 0; j < 4; ++j) {
                // contiguous 1-KB run per (j,kf): conflict-free b128
                const short8 b = *(const short8*)(Bs + ((j * 8 + kf) * 64 + lane) * 8);
                acc[j] = __builtin_amdgcn_mfma_f32_16x16x32_bf16(b, a, acc[j], 0, 0, 0);
            }
        }

        // ---- epilogue (R7-verified): D[row = q*4+reg (o), col = r16 (m)] ----
        if (cb < 4) {
            float* yrow = y1 + (size_t)(m0 + r16) * OUT_ + cb * 64 + q * 4;
#pragma unroll
            for (int j = 0; j < 4; ++j)
                *(f32x4*)(yrow + j * 16) = acc[j];
        } else {
            const int m  = m0 + r16;
            const int bb = (m >= N_) + (m >= 2 * N_) + (m >= 3 * N_);
            const int n  = m - bb * N_;
            unsigned short* rb = y2c + (size_t)(n * B_ + bb) * CW;
#pragma unroll
            for (int j = 0; j < 4; ++j) {
                const int o2  = (cb - 4) * 64 + j * 16 + q * 4;
                const int cch = o2 >> 5;
                const int col = o2 & 31;
                ushort4_t p;
                p.x = f2bf(acc[j][0]); p.y = f2bf(acc[j][1]);
                p.z = f2bf(acc[j][2]); p.w = f2bf(acc[j][3]);
                *(ushort4_t*)(rb + (size_t)cch * CHUNK_ELEMS + col) = p;
            }
        }
    }
}

// ---------------------------------------------------------------------------
// gather_out (unchanged from R6/R7): out[b,n,o] =
//   relu( y1[b,n,o] + (1/cnt) sum_k y2[b,neigh[n,k],o] + bias[o] )
// Chunk c = blockIdx&7 -> XCD; 2.56-MB y2 chunk L2-resident; NT y1 loads;
// NT out stores.
// ---------------------------------------------------------------------------
__global__ __launch_bounds__(256) void gather_out(const unsigned short* __restrict__ y2c,
                                                  const float* __restrict__ y1,
                                                  const int*   __restrict__ neigh,
                                                  const float* __restrict__ bias,
                                                  float* __restrict__ out) {
    const int c   = blockIdx.x & 7;
    const int g   = blockIdx.x >> 3;
    const int n0  = g * 16;
    const int tid = threadIdx.x;

    __shared__ int   idx_s[16 * K_];   // 256 ints
    __shared__ float inv_s[16];

    idx_s[tid] = neigh[n0 * K_ + tid];
    __syncthreads();
    if (tid < 16) {
        int cnt = 0;
#pragma unroll
        for (int k = 0; k < K_; ++k) cnt += idx_s[tid * K_ + k] >= 0 ? 1 : 0;
        inv_s[tid] = 1.0f / (float)(cnt > 1 ? cnt : 1);
    }
    __syncthreads();

    const int q  = tid & 3;          // 8-col group within the 32-col chunk
    const int tl = tid >> 2;         // task 0..63
    const int ns = tl >> 2;          // node_sub 0..15
    const int b  = tl & 3;           // batch

    const unsigned short* ycc = y2c + (size_t)c * CHUNK_ELEMS;

    int jj[K_];
#pragma unroll
    for (int k = 0; k < K_; ++k) jj[k] = idx_s[ns * K_ + k];

    // 16 independent 16-B gather loads from the L2-resident chunk
    ushort8 vv[K_];
#pragma unroll
    for (int k = 0; k < K_; ++k) {
        const int jc = jj[k] >= 0 ? jj[k] : 0;
        vv[k] = *(const ushort8*)(ycc + ((size_t)jc * B_ + b) * CW + q * 8);
    }

    // streaming self term (NT: read-once, keep L2 for the chunk) + bias
    const size_t mo = (size_t)(b * N_ + n0 + ns) * OUT_ + c * CW + q * 8;
    const f32x4 s0 = __builtin_nontemporal_load((const f32x4*)(y1 + mo));
    const f32x4 s1 = __builtin_nontemporal_load((const f32x4*)(y1 + mo + 4));
    const f32x4 b0 = *(const f32x4*)(bias + c * CW + q * 8);
    const f32x4 b1 = *(const f32x4*)(bias + c * CW + q * 8 + 4);

    float acc[8] = {0.f, 0.f, 0.f, 0.f, 0.f, 0.f, 0.f, 0.f};
#pragma unroll
    for (int k = 0; k < K_; ++k) {
        const float m = jj[k] >= 0 ? 1.f : 0.f;
#pragma unroll
        for (int e = 0; e < 8; ++e) acc[e] += bf2f(vv[k][e]) * m;
    }
    const float inv = inv_s[ns];

    f32x4 o0, o1;
#pragma unroll
    for (int e = 0; e < 4; ++e) {
        float v0 = acc[e] * inv + s0[e] + b0[e];
        float v1 = acc[e + 4] * inv + s1[e] + b1[e];
        o0[e] = v0 > 0.f ? v0 : 0.f;
        o1[e] = v1 > 0.f ? v1 : 0.f;
    }
    // out is never re-read: nontemporal stores
    __builtin_nontemporal_store(o0, (f32x4*)(out + mo));
    __builtin_nontemporal_store(o1, (f32x4*)(out + mo + 4));
}

// ---------------------------------------------------------------------------
extern "C" void kernel_launch(void* const* d_in, const int* in_sizes, int n_in,
                              void* d_out, int out_size, void* d_ws, size_t ws_size,
                              hipStream_t stream) {
    const float* x     = (const float*)d_in[0];   // (4, 10000, 256) fp32
    const int*   neigh = (const int*)d_in[1];     // (10000, 16) int32
    const float* W     = (const float*)d_in[2];   // (256, 512) fp32
    const float* bias  = (const float*)d_in[3];   // (256,) fp32
    float*       out   = (float*)d_out;           // (4, 10000, 256) fp32

    unsigned short* WbF = (unsigned short*)d_ws;              // 256 KB frag-major
    float*          y1  = (float*)(WbF + 131072);             // 40000*256 f32 = 41 MB
    unsigned short* y2c = (unsigned short*)(y1 + (size_t)M_ * OUT_);  // 8 x 2.56 MB

    wprep<<<128, 256, 0, stream>>>(W, WbF);
    gemm_pb<<<1024, 256, 0, stream>>>(x, WbF, y1, y2c);   // 8 cb x 128 slots
    gather_out<<<(N_ / 16) * NCH, 256, 0, stream>>>(y2c, y1, neigh, bias, out);
}